// Round 2
// baseline (211.712 us; speedup 1.0000x reference)
//
#include <hip/hip_runtime.h>
#include <hip/hip_cooperative_groups.h>

#define D_FEAT 128
#define EPT_MAX 8   // supports grid >= 512 blocks of 256 threads for 800K edges

namespace cg = cooperative_groups;

// Monotonic float -> uint map: preserves total order, so uint min/max == float min/max.
__device__ __forceinline__ unsigned mapf(float f) {
    unsigned u = __float_as_uint(f);
    return (u & 0x80000000u) ? ~u : (u | 0x80000000u);
}
__device__ __forceinline__ float unmapf(unsigned u) {
    return (u & 0x80000000u) ? __uint_as_float(u & 0x7FFFFFFFu)
                             : __uint_as_float(~u);
}

__global__ __launch_bounds__(256, 4) void fused_mlpgate_kernel(
    const float* __restrict__ h,
    const int*   __restrict__ src,
    const int*   __restrict__ dst,
    const float* __restrict__ W,
    const float* __restrict__ bptr,
    float*       __restrict__ out,
    float*       __restrict__ pu,
    float*       __restrict__ pv,
    unsigned*    __restrict__ g,
    int n_nodes, int n_edges)
{
    cg::grid_group grid = cg::this_grid();
    const int tid  = blockIdx.x * blockDim.x + threadIdx.x;
    const int lane = threadIdx.x & 63;
    const int l31  = lane & 31;
    const int half = lane >> 5;

    // init global min/max slots (ws is poisoned once; must re-init every call)
    if (tid == 0) { g[0] = 0xFFFFFFFFu; g[1] = 0u; }

    // ---- Phase A: per-node projection. 2 nodes per wave, float4 per lane. ----
    {
        const float4* W4 = (const float4*)W;
        const float4 wu = W4[l31];        // W_u fragment
        const float4 wv = W4[32 + l31];   // W_v fragment
        const int wave   = tid >> 6;
        const int nwaves = (gridDim.x * blockDim.x) >> 6;
        for (int base = wave * 2; base < n_nodes; base += nwaves * 2) {
            const int node = base + half;
            float su = 0.f, sv = 0.f;
            if (node < n_nodes) {
                const float4 hv = *reinterpret_cast<const float4*>(
                    h + (size_t)node * D_FEAT + l31 * 4);
                su = hv.x*wu.x + hv.y*wu.y + hv.z*wu.z + hv.w*wu.w;
                sv = hv.x*wv.x + hv.y*wv.y + hv.z*wv.z + hv.w*wv.w;
            }
            #pragma unroll
            for (int off = 16; off > 0; off >>= 1) {   // reduce within 32-lane half
                su += __shfl_xor(su, off, 64);
                sv += __shfl_xor(sv, off, 64);
            }
            if (l31 == 0 && node < n_nodes) { pu[node] = su; pv[node] = sv; }
        }
    }

    grid.sync();

    // ---- Phase B: edge scores in registers + grid min/max via atomics ----
    const int stride = gridDim.x * blockDim.x;
    const float bb = bptr[0];
    float sc[EPT_MAX];
    float vmin =  3.4028235e38f;
    float vmax = -3.4028235e38f;
    #pragma unroll
    for (int k = 0; k < EPT_MAX; ++k) {
        const int e = tid + k * stride;
        float s = 0.f;
        if (e < n_edges) {
            s = pu[src[e]] + pv[dst[e]] + bb;   // pu/pv L2-resident (800 KB)
            vmin = fminf(vmin, s);
            vmax = fmaxf(vmax, s);
        }
        sc[k] = s;
    }
    #pragma unroll
    for (int off = 32; off > 0; off >>= 1) {
        vmin = fminf(vmin, __shfl_xor(vmin, off, 64));
        vmax = fmaxf(vmax, __shfl_xor(vmax, off, 64));
    }
    __shared__ float smin[4], smax[4];
    const int w = threadIdx.x >> 6;
    if (lane == 0) { smin[w] = vmin; smax[w] = vmax; }
    __syncthreads();
    if (threadIdx.x == 0) {
        const float a = fminf(fminf(smin[0], smin[1]), fminf(smin[2], smin[3]));
        const float m = fmaxf(fmaxf(smax[0], smax[1]), fmaxf(smax[2], smax[3]));
        atomicMin(&g[0], mapf(a));
        atomicMax(&g[1], mapf(m));
    }

    grid.sync();

    // ---- Phase C: normalize register-held scores, single coalesced write ----
    const float mn  = unmapf(g[0]);
    const float mx  = unmapf(g[1]);
    const float inv = 1.0f / (mx - mn);
    #pragma unroll
    for (int k = 0; k < EPT_MAX; ++k) {
        const int e = tid + k * stride;
        if (e < n_edges) out[e] = (sc[k] - mn) * inv;
    }
}

extern "C" void kernel_launch(void* const* d_in, const int* in_sizes, int n_in,
                              void* d_out, int out_size, void* d_ws, size_t ws_size,
                              hipStream_t stream) {
    const float* h   = (const float*)d_in[0];
    const int*   src = (const int*)d_in[1];
    const int*   dst = (const int*)d_in[2];
    const float* W   = (const float*)d_in[3];
    const float* b   = (const float*)d_in[4];
    float* out = (float*)d_out;

    int n_nodes = in_sizes[0] / D_FEAT;
    int n_edges = in_sizes[1];

    // workspace: pu[n_nodes], pv[n_nodes], g[2] (uint)
    float* ws = (float*)d_ws;
    float* pu = ws;
    float* pv = ws + n_nodes;
    unsigned* g = (unsigned*)(ws + 2 * n_nodes);

    // Co-resident grid: __launch_bounds__(256,4) -> 4 blocks/CU -> 1024 on 256 CUs.
    // Clamp by the runtime's occupancy answer for safety.
    int perCU = 0;
    (void)hipOccupancyMaxActiveBlocksPerMultiprocessor(
        &perCU, (const void*)fused_mlpgate_kernel, 256, 0);
    if (perCU < 1) perCU = 1;
    int grid = perCU * 256;           // 256 CUs on MI355X
    if (grid > 1024) grid = 1024;     // EPT_MAX=8 needs grid >= 512 for 800K edges
    if (grid < 512)  grid = 512;      // still co-resident (<= 2 blocks/CU is safe)

    void* args[] = { (void*)&h, (void*)&src, (void*)&dst, (void*)&W, (void*)&b,
                     (void*)&out, (void*)&pu, (void*)&pv, (void*)&g,
                     (void*)&n_nodes, (void*)&n_edges };
    hipLaunchCooperativeKernel((const void*)fused_mlpgate_kernel,
                               dim3(grid), dim3(256), args, 0, stream);
}

// Round 3
// 43.092 us; speedup vs baseline: 4.9130x; 4.9130x over previous
//
#include <hip/hip_runtime.h>

#define D_FEAT 128

// Monotonic float -> uint map: preserves order, so uint atomicMin/Max == float min/max.
__device__ __forceinline__ unsigned mapf(float f) {
    unsigned u = __float_as_uint(f);
    return (u & 0x80000000u) ? ~u : (u | 0x80000000u);
}
__device__ __forceinline__ float unmapf(unsigned u) {
    return (u & 0x80000000u) ? __uint_as_float(u & 0x7FFFFFFFu)
                             : __uint_as_float(~u);
}

// K1: per-node projection. 2 nodes per wave (one per 32-lane half), float4/lane.
// Wave reads 1 KB contiguous of h. Also re-inits the global min/max cells.
__global__ __launch_bounds__(256) void proj_kernel(
    const float* __restrict__ h,
    const float* __restrict__ W,
    float* __restrict__ pu,
    float* __restrict__ pv,
    unsigned* __restrict__ g,
    int n_nodes)
{
    if (blockIdx.x == 0 && threadIdx.x == 0) { g[0] = 0xFFFFFFFFu; g[1] = 0u; }

    const int tid  = blockIdx.x * blockDim.x + threadIdx.x;
    const int lane = threadIdx.x & 63;
    const int l31  = lane & 31;
    const int node = ((tid >> 6) << 1) + (lane >> 5);
    if (node >= n_nodes) return;

    const float4* W4 = (const float4*)W;
    const float4 wu = W4[l31];        // W_u fragment (broadcast, L1-hit)
    const float4 wv = W4[32 + l31];   // W_v fragment
    const float4 hv = *reinterpret_cast<const float4*>(
        h + (size_t)node * D_FEAT + l31 * 4);

    float su = hv.x*wu.x + hv.y*wu.y + hv.z*wu.z + hv.w*wu.w;
    float sv = hv.x*wv.x + hv.y*wv.y + hv.z*wv.z + hv.w*wv.w;

    #pragma unroll
    for (int off = 16; off > 0; off >>= 1) {   // xor 16..1 stays within each 32-half
        su += __shfl_xor(su, off, 64);
        sv += __shfl_xor(sv, off, 64);
    }
    if (l31 == 0) { pu[node] = su; pv[node] = sv; }
}

// K2: 4 edges/thread. score -> out (raw), block min/max -> 2 atomics to g.
__global__ __launch_bounds__(256) void score_kernel(
    const int*   __restrict__ src,
    const int*   __restrict__ dst,
    const float* __restrict__ pu,
    const float* __restrict__ pv,
    const float* __restrict__ bptr,
    float*       __restrict__ out,
    unsigned*    __restrict__ g,
    int n4, int n_edges)
{
    const int i = blockIdx.x * blockDim.x + threadIdx.x;
    float vmin =  3.4028235e38f;
    float vmax = -3.4028235e38f;

    if (i < n4) {
        const float bb = bptr[0];
        const int4 s4 = reinterpret_cast<const int4*>(src)[i];
        const int4 d4 = reinterpret_cast<const int4*>(dst)[i];
        float4 o;
        o.x = pu[s4.x] + pv[d4.x] + bb;   // pu/pv: 800 KB total, L2-resident
        o.y = pu[s4.y] + pv[d4.y] + bb;
        o.z = pu[s4.z] + pv[d4.z] + bb;
        o.w = pu[s4.w] + pv[d4.w] + bb;
        reinterpret_cast<float4*>(out)[i] = o;
        vmin = fminf(fminf(o.x, o.y), fminf(o.z, o.w));
        vmax = fmaxf(fmaxf(o.x, o.y), fmaxf(o.z, o.w));
        // tail (n_edges % 4) handled by the last vector thread
        if (i == n4 - 1) {
            for (int e = n4 * 4; e < n_edges; ++e) {
                float s = pu[src[e]] + pv[dst[e]] + bb;
                out[e] = s;
                vmin = fminf(vmin, s);
                vmax = fmaxf(vmax, s);
            }
        }
    }

    #pragma unroll
    for (int off = 32; off > 0; off >>= 1) {
        vmin = fminf(vmin, __shfl_xor(vmin, off, 64));
        vmax = fmaxf(vmax, __shfl_xor(vmax, off, 64));
    }
    __shared__ float smin[4], smax[4];
    const int w = threadIdx.x >> 6;
    if ((threadIdx.x & 63) == 0) { smin[w] = vmin; smax[w] = vmax; }
    __syncthreads();
    if (threadIdx.x == 0) {
        const float a = fminf(fminf(smin[0], smin[1]), fminf(smin[2], smin[3]));
        const float m = fmaxf(fmaxf(smax[0], smax[1]), fmaxf(smax[2], smax[3]));
        atomicMin(&g[0], mapf(a));
        atomicMax(&g[1], mapf(m));
    }
}

// K3: in-place normalize, float4.
__global__ __launch_bounds__(256) void norm_kernel(
    float* __restrict__ out,
    const unsigned* __restrict__ g,
    int n4, int n_edges)
{
    const int i = blockIdx.x * blockDim.x + threadIdx.x;
    if (i >= n4) return;
    const float mn  = unmapf(g[0]);
    const float inv = 1.0f / (unmapf(g[1]) - mn);
    float4 v = reinterpret_cast<const float4*>(out)[i];
    v.x = (v.x - mn) * inv;
    v.y = (v.y - mn) * inv;
    v.z = (v.z - mn) * inv;
    v.w = (v.w - mn) * inv;
    reinterpret_cast<float4*>(out)[i] = v;
    if (i == n4 - 1) {
        for (int e = n4 * 4; e < n_edges; ++e)
            out[e] = (out[e] - mn) * inv;
    }
}

extern "C" void kernel_launch(void* const* d_in, const int* in_sizes, int n_in,
                              void* d_out, int out_size, void* d_ws, size_t ws_size,
                              hipStream_t stream) {
    const float* h   = (const float*)d_in[0];
    const int*   src = (const int*)d_in[1];
    const int*   dst = (const int*)d_in[2];
    const float* W   = (const float*)d_in[3];
    const float* b   = (const float*)d_in[4];
    float* out = (float*)d_out;

    const int n_nodes = in_sizes[0] / D_FEAT;
    const int n_edges = in_sizes[1];

    // workspace: pu[n_nodes], pv[n_nodes], g[2] (uint)
    float* ws = (float*)d_ws;
    float* pu = ws;
    float* pv = ws + n_nodes;
    unsigned* g = (unsigned*)(ws + 2 * n_nodes);

    // K1: 8 nodes per 256-thread block (4 waves x 2 nodes)
    {
        const int blocks = (n_nodes + 7) / 8;
        proj_kernel<<<blocks, 256, 0, stream>>>(h, W, pu, pv, g, n_nodes);
    }
    // K2: 4 edges/thread
    const int n4 = n_edges >> 2;
    {
        const int blocks = (n4 + 255) / 256;
        score_kernel<<<blocks, 256, 0, stream>>>(src, dst, pu, pv, b, out, g, n4, n_edges);
    }
    // K3: normalize in place
    {
        const int blocks = (n4 + 255) / 256;
        norm_kernel<<<blocks, 256, 0, stream>>>(out, g, n4, n_edges);
    }
}